// Round 14
// baseline (8751.037 us; speedup 1.0000x reference)
//
#include <hip/hip_runtime.h>
#include <hip/hip_bf16.h>
#include <stdint.h>

#define N_ 256
#define T_ 128
#define D_ 1024
#define H_ 1024
#define FH_ 4096
#define K2_ 2048

typedef __bf16 bf16x8 __attribute__((ext_vector_type(8)));
typedef float f32x4 __attribute__((ext_vector_type(4)));

// ---------------- transpose + cast fp32 -> bf16 ----------------
// dst[c][dst_coloff + r] = (bf16) src[r][c]
__global__ __launch_bounds__(256) void transpose_cast(
    const float* __restrict__ src, int cols,
    __hip_bfloat16* __restrict__ dst, int dst_stride, int dst_coloff)
{
    __shared__ float tile[32][33];
    int cb = blockIdx.x * 32, rb = blockIdx.y * 32;
    int tx = threadIdx.x, ty = threadIdx.y;  // (32, 8)
#pragma unroll
    for (int i = 0; i < 4; i++)
        tile[ty + i * 8][tx] = src[(size_t)(rb + ty + i * 8) * cols + cb + tx];
    __syncthreads();
#pragma unroll
    for (int i = 0; i < 4; i++)
        dst[(size_t)(cb + ty + i * 8) * dst_stride + dst_coloff + rb + tx] =
            __float2bfloat16(tile[tx][ty + i * 8]);
}

// ---------------- xproj GEMM: xpb[tl][n][j] = x[n][t0+tl] @ Wx (bf16) -----
#define BM 64
#define BN 128
#define BK 64
#define BKP 72

__global__ __launch_bounds__(256) void gemm_x(
    const float* __restrict__ Xf,
    const __hip_bfloat16* __restrict__ BT,
    __hip_bfloat16* __restrict__ Cp, int t0)
{
    __shared__ __hip_bfloat16 Al[BM][BKP];
    __shared__ __hip_bfloat16 Bl[BN][BKP];
    const int tid = threadIdx.x;
    const int lane = tid & 63, wid = tid >> 6;
    const int lin = blockIdx.y * gridDim.x + blockIdx.x;
    const int cti = (lin & 7) + 8 * ((lin >> 3) & 3);   // 0..31 col tile
    const int mti = lin >> 5;                           // row tile
    const int m0 = mti * BM, n0 = cti * BN;
    const int wm = (wid >> 1) * 32, wn = (wid & 1) * 64;
    const int rs = tid >> 3, kc = (tid & 7) * 8;
    f32x4 acc[2][4] = {};

    for (int k0 = 0; k0 < D_; k0 += BK) {
#pragma unroll
        for (int p = 0; p < BM; p += 32) {
            int r = rs + p;
            int g = m0 + r;
            int nn = g & 255, tl = g >> 8;
            const float* s = Xf + ((size_t)nn * T_ + (t0 + tl)) * D_ + k0 + kc;
            float4 v0 = *reinterpret_cast<const float4*>(s);
            float4 v1 = *reinterpret_cast<const float4*>(s + 4);
            __hip_bfloat16 h8[8];
            h8[0] = __float2bfloat16(v0.x); h8[1] = __float2bfloat16(v0.y);
            h8[2] = __float2bfloat16(v0.z); h8[3] = __float2bfloat16(v0.w);
            h8[4] = __float2bfloat16(v1.x); h8[5] = __float2bfloat16(v1.y);
            h8[6] = __float2bfloat16(v1.z); h8[7] = __float2bfloat16(v1.w);
            *reinterpret_cast<int4*>(&Al[r][kc]) = *reinterpret_cast<const int4*>(h8);
        }
#pragma unroll
        for (int p = 0; p < BN; p += 32) {
            int r = rs + p;
            const __hip_bfloat16* s = BT + (size_t)(n0 + r) * D_ + k0 + kc;
            *reinterpret_cast<int4*>(&Bl[r][kc]) = *reinterpret_cast<const int4*>(s);
        }
        __syncthreads();
        const int ko = (lane >> 4) * 8;
#pragma unroll
        for (int kk = 0; kk < BK; kk += 32) {
            bf16x8 a0 = *reinterpret_cast<const bf16x8*>(&Al[wm + (lane & 15)][kk + ko]);
            bf16x8 a1 = *reinterpret_cast<const bf16x8*>(&Al[wm + 16 + (lane & 15)][kk + ko]);
#pragma unroll
            for (int ni = 0; ni < 4; ni++) {
                bf16x8 bq = *reinterpret_cast<const bf16x8*>(&Bl[wn + ni * 16 + (lane & 15)][kk + ko]);
                acc[0][ni] = __builtin_amdgcn_mfma_f32_16x16x32_bf16(a0, bq, acc[0][ni], 0, 0, 0);
                acc[1][ni] = __builtin_amdgcn_mfma_f32_16x16x32_bf16(a1, bq, acc[1][ni], 0, 0, 0);
            }
        }
        __syncthreads();
    }
    const int cr = (lane >> 4) * 4, ccol = lane & 15;
#pragma unroll
    for (int mi = 0; mi < 2; mi++)
#pragma unroll
        for (int ni = 0; ni < 4; ni++)
#pragma unroll
            for (int r = 0; r < 4; r++) {
                size_t idx = (size_t)(m0 + wm + mi * 16 + cr + r) * FH_ + (n0 + wn + ni * 16 + ccol);
                Cp[idx] = __float2bfloat16(acc[mi][ni][r]);
            }
}

// ---------------- A -> bf16 cast (layout preserved [n][1024][16]) ---------
__global__ __launch_bounds__(256) void abf_cast(
    const float* __restrict__ A, __hip_bfloat16* __restrict__ Abf)
{
    size_t i = ((size_t)blockIdx.x * 256 + threadIdx.x) * 4;
    float4 v = *reinterpret_cast<const float4*>(A + i);
    __hip_bfloat16 o[4];
    o[0] = __float2bfloat16(v.x); o[1] = __float2bfloat16(v.y);
    o[2] = __float2bfloat16(v.z); o[3] = __float2bfloat16(v.w);
    *reinterpret_cast<uint2*>(Abf + i) = *reinterpret_cast<uint2*>(o);
}

// ---------------- init: h0 + c0 only ----------------
__global__ __launch_bounds__(256) void init_p(
    const float* __restrict__ A, float* __restrict__ cbuf,
    __hip_bfloat16* __restrict__ hb0)
{
    const int n = blockIdx.x, tid = threadIdx.x;
    float hv[4];
#pragma unroll
    for (int q = 0; q < 4; q++) {
        const float4* Ap = reinterpret_cast<const float4*>(A + ((size_t)n * H_ + tid * 4 + q) * 16);
        float4 q0 = Ap[0], q1 = Ap[1], q2 = Ap[2], q3 = Ap[3];
        float s = q0.x + q0.y + q0.z + q0.w + q1.x + q1.y + q1.z + q1.w
                + q2.x + q2.y + q2.z + q2.w + q3.x + q3.y + q3.z + q3.w;
        hv[q] = s * 0.0625f;
    }
    *reinterpret_cast<float4*>(cbuf + (size_t)n * H_ + tid * 4) = *reinterpret_cast<float4*>(hv);
    __hip_bfloat16 h4[4];
#pragma unroll
    for (int q = 0; q < 4; q++) h4[q] = __float2bfloat16(hv[q]);
    *reinterpret_cast<uint2*>(hb0 + (size_t)n * K2_ + tid * 4) = *reinterpret_cast<uint2*>(h4);
}

// ---------------- wattn2: scores + softmax + attn, one n per WG ----------
__global__ __launch_bounds__(256) void wattn2(
    __hip_bfloat16* __restrict__ hbt,
    const __hip_bfloat16* __restrict__ Abf)
{
    __shared__ float red[4][16];
    const int n = blockIdx.x, tid = threadIdx.x;
    const int lane = tid & 63, wv4 = tid >> 6;

    float h4[4];
    {
        uint2 hraw = *reinterpret_cast<const uint2*>(hbt + (size_t)n * K2_ + tid * 4);
        __hip_bfloat16 hb4[4];
        *reinterpret_cast<uint2*>(hb4) = hraw;
#pragma unroll
        for (int q = 0; q < 4; q++) h4[q] = __bfloat162float(hb4[q]);
    }
    bf16x8 a[4][2];
    const __hip_bfloat16* ap = Abf + ((size_t)n * H_ + tid * 4) * 16;
#pragma unroll
    for (int q = 0; q < 4; q++) {
        a[q][0] = *reinterpret_cast<const bf16x8*>(ap + q * 16);
        a[q][1] = *reinterpret_cast<const bf16x8*>(ap + q * 16 + 8);
    }
    float spv[16];
#pragma unroll
    for (int l = 0; l < 8; l++) {
        spv[l]     = h4[0] * (float)a[0][0][l] + h4[1] * (float)a[1][0][l]
                   + h4[2] * (float)a[2][0][l] + h4[3] * (float)a[3][0][l];
        spv[l + 8] = h4[0] * (float)a[0][1][l] + h4[1] * (float)a[1][1][l]
                   + h4[2] * (float)a[2][1][l] + h4[3] * (float)a[3][1][l];
    }
#pragma unroll
    for (int l = 0; l < 16; l++) {
        spv[l] += __shfl_xor(spv[l], 1);  spv[l] += __shfl_xor(spv[l], 2);
        spv[l] += __shfl_xor(spv[l], 4);  spv[l] += __shfl_xor(spv[l], 8);
        spv[l] += __shfl_xor(spv[l], 16); spv[l] += __shfl_xor(spv[l], 32);
    }
    if (lane == 0) {
#pragma unroll
        for (int l = 0; l < 16; l++) red[wv4][l] = spv[l];
    }
    __syncthreads();
    float w[16], se = 0.f;
    {
        float sc[16], m;
#pragma unroll
        for (int l = 0; l < 16; l++)
            sc[l] = (red[0][l] + red[1][l] + red[2][l] + red[3][l]) * 0.03125f;
        m = sc[0];
#pragma unroll
        for (int l = 1; l < 16; l++) m = fmaxf(m, sc[l]);
#pragma unroll
        for (int l = 0; l < 16; l++) { w[l] = __expf(sc[l] - m); se += w[l]; }
        float inv = 1.f / se;
#pragma unroll
        for (int l = 0; l < 16; l++) w[l] *= inv;
    }
    __hip_bfloat16 o4[4];
#pragma unroll
    for (int q = 0; q < 4; q++) {
        float s = 0.f;
#pragma unroll
        for (int l = 0; l < 8; l++) s += w[l] * (float)a[q][0][l];
#pragma unroll
        for (int l = 0; l < 8; l++) s += w[l + 8] * (float)a[q][1][l];
        o4[q] = __float2bfloat16(s);
    }
    *reinterpret_cast<uint2*>(hbt + (size_t)n * K2_ + H_ + tid * 4) =
        *reinterpret_cast<uint2*>(o4);
}

// ---------------- step GEMM + gates, XCD-clustered, 2-deep prefetch -------
// 512 WGs x 256 thr. bid = xcd + 8*k; ct = (bid&7)+8*(k&7) (16 cols x 4
// sections), r = k>>3 (32 n-rows). K = 2048, BK = 128, double-buffered LDS,
// TWO register load sets: load k+2 while writing k+1 and computing k.
#define LDAp 136

__global__ __launch_bounds__(256) void step_gemm(
    const __hip_bfloat16* __restrict__ hb_in,
    __hip_bfloat16* __restrict__ hb_out,
    const __hip_bfloat16* __restrict__ W2T,
    const __hip_bfloat16* __restrict__ xp,   // [256][4096] bf16, this t
    const float* __restrict__ bias,
    float* __restrict__ cbuf,
    float* __restrict__ out, int t)
{
    // A0 [0,8704) A1 [8704,17408) B0 [17408,34816) B1 [34816,52224)
    __shared__ __align__(16) char smem[52224];
    float* pls = (float*)smem;  // [32][68] fp32, aliases A0 after K-loop

    const int tid = threadIdx.x;
    const int lane = tid & 63, wv = tid >> 6;       // wv = gate section
    const int bid = blockIdx.x;
    const int k = bid >> 3;
    const int ct = (bid & 7) + 8 * (k & 7);         // 0..63, XCD = ct%8
    const int r  = k >> 3;                          // 0..7
    const int hc0 = ct * 16, n0 = r * 32;
    const int rs = tid >> 4;                        // 0..15
    const int kc = (tid & 15) * 8;
    const int l15 = lane & 15, ko8 = (lane >> 4) * 8;

    const __hip_bfloat16* aS0 = hb_in + (size_t)(n0 + rs) * K2_ + kc;
    const __hip_bfloat16* aS1 = hb_in + (size_t)(n0 + rs + 16) * K2_ + kc;
    const __hip_bfloat16* bS0 = W2T + (size_t)(0 * 1024 + hc0 + rs) * K2_ + kc;
    const __hip_bfloat16* bS1 = W2T + (size_t)(1 * 1024 + hc0 + rs) * K2_ + kc;
    const __hip_bfloat16* bS2 = W2T + (size_t)(2 * 1024 + hc0 + rs) * K2_ + kc;
    const __hip_bfloat16* bS3 = W2T + (size_t)(3 * 1024 + hc0 + rs) * K2_ + kc;

    // two register load sets (even/odd k-blocks)
    int4 rA0[2], rA1[2], rB0[2], rB1[2], rB2[2], rB3[2];
    auto LOAD = [&](int set, int k0) {
        rA0[set] = *reinterpret_cast<const int4*>(aS0 + k0);
        rA1[set] = *reinterpret_cast<const int4*>(aS1 + k0);
        rB0[set] = *reinterpret_cast<const int4*>(bS0 + k0);
        rB1[set] = *reinterpret_cast<const int4*>(bS1 + k0);
        rB2[set] = *reinterpret_cast<const int4*>(bS2 + k0);
        rB3[set] = *reinterpret_cast<const int4*>(bS3 + k0);
    };
    auto WRITE = [&](int b, int set) {
        __hip_bfloat16* Al = (__hip_bfloat16*)(smem + b * 8704);
        __hip_bfloat16* Bl = (__hip_bfloat16*)(smem + 17408 + b * 17408);
        *reinterpret_cast<int4*>(Al + rs * LDAp + kc) = rA0[set];
        *reinterpret_cast<int4*>(Al + (rs + 16) * LDAp + kc) = rA1[set];
        *reinterpret_cast<int4*>(Bl + rs * LDAp + kc) = rB0[set];
        *reinterpret_cast<int4*>(Bl + (rs + 16) * LDAp + kc) = rB1[set];
        *reinterpret_cast<int4*>(Bl + (rs + 32) * LDAp + kc) = rB2[set];
        *reinterpret_cast<int4*>(Bl + (rs + 48) * LDAp + kc) = rB3[set];
    };

    // prologue: k=0 -> buf0 ; k=1 loaded into set1 (written at end of it=0)
    LOAD(0, 0);
    WRITE(0, 0);
    LOAD(1, 128);
    __syncthreads();

    f32x4 acc0{}, acc1{};
#pragma unroll 1
    for (int it = 0; it < 16; ++it) {
        // issue load of k-block it+2 into the set consumed at end of prev iter
        if (it < 14) LOAD(it & 1, (it + 2) * 128);
        const int cur = it & 1;
        const __hip_bfloat16* pA = (const __hip_bfloat16*)(smem + cur * 8704) + l15 * LDAp + ko8;
        const __hip_bfloat16* pB = (const __hip_bfloat16*)(smem + 17408 + cur * 17408)
                                   + (wv * 16 + l15) * LDAp + ko8;
#pragma unroll
        for (int kf = 0; kf < 4; kf++) {
            bf16x8 a0 = *reinterpret_cast<const bf16x8*>(pA + kf * 32);
            bf16x8 a1 = *reinterpret_cast<const bf16x8*>(pA + 16 * LDAp + kf * 32);
            bf16x8 bq = *reinterpret_cast<const bf16x8*>(pB + kf * 32);
            acc0 = __builtin_amdgcn_mfma_f32_16x16x32_bf16(a0, bq, acc0, 0, 0, 0);
            acc1 = __builtin_amdgcn_mfma_f32_16x16x32_bf16(a1, bq, acc1, 0, 0, 0);
        }
        __syncthreads();                 // all waves done reading buf[cur]
        if (it < 15) {
            WRITE(cur ^ 1, (it + 1) & 1);  // k-block it+1, loaded 1-2 iters ago
            __syncthreads();               // next-buf writes visible
        }
    }

    // pls: [32 n][sec*16 + col]  (aliases A0; safe after final barrier)
    {
        const int cr = (lane >> 4) * 4;
#pragma unroll
        for (int r4 = 0; r4 < 4; r4++) {
            pls[(cr + r4) * 68 + wv * 16 + l15]      = acc0[r4];
            pls[(16 + cr + r4) * 68 + wv * 16 + l15] = acc1[r4];
        }
    }
    __syncthreads();

    // ---- epilogue: thread -> (n_l = tid>>3, 2 cols at (tid&7)*2) ----
    {
        const int n_l = tid >> 3, c2 = (tid & 7) * 2;
        const int nn = n0 + n_l;
        float hv2[2], cv2[2];
        const size_t cbase = (size_t)nn * H_ + hc0 + c2;
        float2 cold = *reinterpret_cast<const float2*>(cbuf + cbase);
        cv2[0] = cold.x; cv2[1] = cold.y;
#pragma unroll
        for (int cc = 0; cc < 2; cc++) {
            const int c = c2 + cc;
            float pre[4];
#pragma unroll
            for (int s = 0; s < 4; s++) {
                const int gj = s * 1024 + hc0 + c;
                pre[s] = pls[n_l * 68 + s * 16 + c]
                       + __bfloat162float(xp[(size_t)nn * FH_ + gj]) + bias[gj];
            }
            float iv = 1.f / (1.f + __expf(-pre[0]));
            float fv = 1.f / (1.f + __expf(-pre[1]));
            float ov = 1.f / (1.f + __expf(-pre[2]));
            float gx = fminf(fmaxf(pre[3], -20.f), 20.f);
            float eg = __expf(2.f * gx);
            float gv = (eg - 1.f) / (eg + 1.f);
            float c2v = fv * cv2[cc] + iv * gv;
            cv2[cc] = c2v;
            float cx = fminf(fmaxf(c2v, -20.f), 20.f);
            float ec = __expf(2.f * cx);
            hv2[cc] = ov * (ec - 1.f) / (ec + 1.f);
        }
        *reinterpret_cast<float2*>(cbuf + cbase) = make_float2(cv2[0], cv2[1]);
        *reinterpret_cast<float2*>(out + ((size_t)nn * T_ + t) * H_ + hc0 + c2) =
            make_float2(hv2[0], hv2[1]);
        __hip_bfloat16 h2[2];
        h2[0] = __float2bfloat16(hv2[0]);
        h2[1] = __float2bfloat16(hv2[1]);
        *reinterpret_cast<uint32_t*>(hb_out + (size_t)nn * K2_ + hc0 + c2) =
            *reinterpret_cast<uint32_t*>(h2);
    }
}

extern "C" void kernel_launch(void* const* d_in, const int* in_sizes, int n_in,
                              void* d_out, int out_size, void* d_ws, size_t ws_size,
                              hipStream_t stream)
{
    const float* x     = (const float*)d_in[0];
    const float* A     = (const float*)d_in[1];
    const float* Wx    = (const float*)d_in[2];
    const float* Wh    = (const float*)d_in[3];
    const float* Wattn = (const float*)d_in[4];
    const float* b     = (const float*)d_in[5];
    float* out = (float*)d_out;
    char* ws = (char*)d_ws;
    dim3 tb(32, 8);

    const size_t SZ_W2T = (size_t)FH_ * K2_ * 2;       // 16.8 MB  [Wh;Wattn]^T
    const size_t SZ_WxT = (size_t)FH_ * D_ * 2;        // 8.4 MB
    const size_t SZ_Abf = (size_t)N_ * H_ * 16 * 2;    // 8.4 MB
    const size_t SZ_HB  = (size_t)N_ * K2_ * 2;        // 1 MB (x2)
    const size_t SZ_C   = (size_t)N_ * H_ * 4;         // 1 MB
    const size_t SZ_XPT = (size_t)N_ * FH_ * 2;        // 2.1 MB per timestep

    size_t off = 0;
    __hip_bfloat16* W2T = (__hip_bfloat16*)(ws + off); off += SZ_W2T;
    __hip_bfloat16* WxT = (__hip_bfloat16*)(ws + off); off += SZ_WxT;
    __hip_bfloat16* Abf = (__hip_bfloat16*)(ws + off); off += SZ_Abf;
    __hip_bfloat16* hbA = (__hip_bfloat16*)(ws + off); off += SZ_HB;
    __hip_bfloat16* hbB = (__hip_bfloat16*)(ws + off); off += SZ_HB;
    float* cbuf = (float*)(ws + off); off += SZ_C;
    __hip_bfloat16* xpb = (__hip_bfloat16*)(ws + off);

    size_t rem = (ws_size > off) ? (ws_size - off) : 0;
    int TC = 64;
    while (TC > 1 && (size_t)TC * SZ_XPT > rem) TC >>= 1;

    // ---- weight / A prep ----
    transpose_cast<<<dim3(FH_ / 32, H_ / 32), tb, 0, stream>>>(Wh, FH_, W2T, K2_, 0);
    transpose_cast<<<dim3(FH_ / 32, H_ / 32), tb, 0, stream>>>(Wattn, FH_, W2T, K2_, H_);
    transpose_cast<<<dim3(FH_ / 32, D_ / 32), tb, 0, stream>>>(Wx, FH_, WxT, D_, 0);
    abf_cast<<<dim3((N_ * H_ * 16) / 1024), 256, 0, stream>>>(A, Abf);
    init_p<<<N_, 256, 0, stream>>>(A, cbuf, hbA);

    __hip_bfloat16* hbp[2] = {hbA, hbB};
    for (int t0 = 0; t0 < T_; t0 += TC) {
        int tc = (T_ - t0 < TC) ? (T_ - t0) : TC;
        gemm_x<<<dim3(FH_ / BN, tc * N_ / BM), 256, 0, stream>>>(x, WxT, xpb, t0);
        for (int tl = 0; tl < tc; tl++) {
            int t = t0 + tl;
            // scores + softmax + attn for step t (fills attn-half of hb[t&1])
            wattn2<<<N_, 256, 0, stream>>>(hbp[t & 1], Abf);
            // GEMM K=2048 + gates; writes h-half of hb[(t+1)&1]
            step_gemm<<<dim3(512), 256, 0, stream>>>(
                hbp[t & 1], hbp[(t + 1) & 1], W2T,
                xpb + (size_t)tl * N_ * FH_, b, cbuf, out, t);
        }
    }
}

// Round 15
// 3069.012 us; speedup vs baseline: 2.8514x; 2.8514x over previous
//
#include <hip/hip_runtime.h>
#include <hip/hip_bf16.h>
#include <stdint.h>

#define N_ 256
#define T_ 128
#define D_ 1024
#define H_ 1024
#define FH_ 4096
#define K2_ 2048

typedef __bf16 bf16x8 __attribute__((ext_vector_type(8)));
typedef float f32x4 __attribute__((ext_vector_type(4)));

// ---------------- transpose + cast fp32 -> bf16 ----------------
// dst[c][dst_coloff + r] = (bf16) src[r][c]
__global__ __launch_bounds__(256) void transpose_cast(
    const float* __restrict__ src, int cols,
    __hip_bfloat16* __restrict__ dst, int dst_stride, int dst_coloff)
{
    __shared__ float tile[32][33];
    int cb = blockIdx.x * 32, rb = blockIdx.y * 32;
    int tx = threadIdx.x, ty = threadIdx.y;  // (32, 8)
#pragma unroll
    for (int i = 0; i < 4; i++)
        tile[ty + i * 8][tx] = src[(size_t)(rb + ty + i * 8) * cols + cb + tx];
    __syncthreads();
#pragma unroll
    for (int i = 0; i < 4; i++)
        dst[(size_t)(cb + ty + i * 8) * dst_stride + dst_coloff + rb + tx] =
            __float2bfloat16(tile[tx][ty + i * 8]);
}

// ---------------- xproj GEMM: xpb[tl][n][j] = x[n][t0+tl] @ Wx (bf16) -----
// XCD-swizzled tile mapping: 4 B-panels pinned per XCD for L2 reuse.
#define BM 64
#define BN 128
#define BK 64
#define BKP 72

__global__ __launch_bounds__(256) void gemm_x(
    const float* __restrict__ Xf,
    const __hip_bfloat16* __restrict__ BT,
    __hip_bfloat16* __restrict__ Cp, int t0)
{
    __shared__ __hip_bfloat16 Al[BM][BKP];
    __shared__ __hip_bfloat16 Bl[BN][BKP];
    const int tid = threadIdx.x;
    const int lane = tid & 63, wid = tid >> 6;
    // swizzle: same-XCD blocks share B-panels
    const int lin = blockIdx.y * gridDim.x + blockIdx.x;
    const int cti = (lin & 7) + 8 * ((lin >> 3) & 3);   // 0..31 col tile
    const int mti = lin >> 5;                           // row tile
    const int m0 = mti * BM, n0 = cti * BN;
    const int wm = (wid >> 1) * 32, wn = (wid & 1) * 64;
    const int rs = tid >> 3, kc = (tid & 7) * 8;
    f32x4 acc[2][4] = {};

    for (int k0 = 0; k0 < D_; k0 += BK) {
#pragma unroll
        for (int p = 0; p < BM; p += 32) {
            int r = rs + p;
            int g = m0 + r;
            int nn = g & 255, tl = g >> 8;
            const float* s = Xf + ((size_t)nn * T_ + (t0 + tl)) * D_ + k0 + kc;
            float4 v0 = *reinterpret_cast<const float4*>(s);
            float4 v1 = *reinterpret_cast<const float4*>(s + 4);
            __hip_bfloat16 h8[8];
            h8[0] = __float2bfloat16(v0.x); h8[1] = __float2bfloat16(v0.y);
            h8[2] = __float2bfloat16(v0.z); h8[3] = __float2bfloat16(v0.w);
            h8[4] = __float2bfloat16(v1.x); h8[5] = __float2bfloat16(v1.y);
            h8[6] = __float2bfloat16(v1.z); h8[7] = __float2bfloat16(v1.w);
            *reinterpret_cast<int4*>(&Al[r][kc]) = *reinterpret_cast<const int4*>(h8);
        }
#pragma unroll
        for (int p = 0; p < BN; p += 32) {
            int r = rs + p;
            const __hip_bfloat16* s = BT + (size_t)(n0 + r) * D_ + k0 + kc;
            *reinterpret_cast<int4*>(&Bl[r][kc]) = *reinterpret_cast<const int4*>(s);
        }
        __syncthreads();
        const int ko = (lane >> 4) * 8;
#pragma unroll
        for (int kk = 0; kk < BK; kk += 32) {
            bf16x8 a0 = *reinterpret_cast<const bf16x8*>(&Al[wm + (lane & 15)][kk + ko]);
            bf16x8 a1 = *reinterpret_cast<const bf16x8*>(&Al[wm + 16 + (lane & 15)][kk + ko]);
#pragma unroll
            for (int ni = 0; ni < 4; ni++) {
                bf16x8 bq = *reinterpret_cast<const bf16x8*>(&Bl[wn + ni * 16 + (lane & 15)][kk + ko]);
                acc[0][ni] = __builtin_amdgcn_mfma_f32_16x16x32_bf16(a0, bq, acc[0][ni], 0, 0, 0);
                acc[1][ni] = __builtin_amdgcn_mfma_f32_16x16x32_bf16(a1, bq, acc[1][ni], 0, 0, 0);
            }
        }
        __syncthreads();
    }
    const int cr = (lane >> 4) * 4, ccol = lane & 15;
#pragma unroll
    for (int mi = 0; mi < 2; mi++)
#pragma unroll
        for (int ni = 0; ni < 4; ni++)
#pragma unroll
            for (int r = 0; r < 4; r++) {
                size_t idx = (size_t)(m0 + wm + mi * 16 + cr + r) * FH_ + (n0 + wn + ni * 16 + ccol);
                Cp[idx] = __float2bfloat16(acc[mi][ni][r]);
            }
}

// ---------------- A -> bf16 cast (layout preserved [n][1024][16]) ---------
__global__ __launch_bounds__(256) void abf_cast(
    const float* __restrict__ A, __hip_bfloat16* __restrict__ Abf)
{
    size_t i = ((size_t)blockIdx.x * 256 + threadIdx.x) * 4;
    float4 v = *reinterpret_cast<const float4*>(A + i);
    __hip_bfloat16 o[4];
    o[0] = __float2bfloat16(v.x); o[1] = __float2bfloat16(v.y);
    o[2] = __float2bfloat16(v.z); o[3] = __float2bfloat16(v.w);
    *reinterpret_cast<uint2*>(Abf + i) = *reinterpret_cast<uint2*>(o);
}

// ---------------- init: h0 + c0 only ----------------
__global__ __launch_bounds__(256) void init_p(
    const float* __restrict__ A, float* __restrict__ cbuf,
    __hip_bfloat16* __restrict__ hb0)
{
    const int n = blockIdx.x, tid = threadIdx.x;
    float hv[4];
#pragma unroll
    for (int q = 0; q < 4; q++) {
        const float4* Ap = reinterpret_cast<const float4*>(A + ((size_t)n * H_ + tid * 4 + q) * 16);
        float4 q0 = Ap[0], q1 = Ap[1], q2 = Ap[2], q3 = Ap[3];
        float s = q0.x + q0.y + q0.z + q0.w + q1.x + q1.y + q1.z + q1.w
                + q2.x + q2.y + q2.z + q2.w + q3.x + q3.y + q3.z + q3.w;
        hv[q] = s * 0.0625f;
    }
    *reinterpret_cast<float4*>(cbuf + (size_t)n * H_ + tid * 4) = *reinterpret_cast<float4*>(hv);
    __hip_bfloat16 h4[4];
#pragma unroll
    for (int q = 0; q < 4; q++) h4[q] = __float2bfloat16(hv[q]);
    *reinterpret_cast<uint2*>(hb0 + (size_t)n * K2_ + tid * 4) = *reinterpret_cast<uint2*>(h4);
}

// ---------------- wattn2: scores + softmax + attn, one n per WG ----------
__global__ __launch_bounds__(256) void wattn2(
    __hip_bfloat16* __restrict__ hbt,
    const __hip_bfloat16* __restrict__ Abf)
{
    __shared__ float red[4][16];
    const int n = blockIdx.x, tid = threadIdx.x;
    const int lane = tid & 63, wv4 = tid >> 6;

    float h4[4];
    {
        uint2 hraw = *reinterpret_cast<const uint2*>(hbt + (size_t)n * K2_ + tid * 4);
        __hip_bfloat16 hb4[4];
        *reinterpret_cast<uint2*>(hb4) = hraw;
#pragma unroll
        for (int q = 0; q < 4; q++) h4[q] = __bfloat162float(hb4[q]);
    }
    bf16x8 a[4][2];
    const __hip_bfloat16* ap = Abf + ((size_t)n * H_ + tid * 4) * 16;
#pragma unroll
    for (int q = 0; q < 4; q++) {
        a[q][0] = *reinterpret_cast<const bf16x8*>(ap + q * 16);
        a[q][1] = *reinterpret_cast<const bf16x8*>(ap + q * 16 + 8);
    }
    float spv[16];
#pragma unroll
    for (int l = 0; l < 8; l++) {
        spv[l]     = h4[0] * (float)a[0][0][l] + h4[1] * (float)a[1][0][l]
                   + h4[2] * (float)a[2][0][l] + h4[3] * (float)a[3][0][l];
        spv[l + 8] = h4[0] * (float)a[0][1][l] + h4[1] * (float)a[1][1][l]
                   + h4[2] * (float)a[2][1][l] + h4[3] * (float)a[3][1][l];
    }
#pragma unroll
    for (int l = 0; l < 16; l++) {
        spv[l] += __shfl_xor(spv[l], 1);  spv[l] += __shfl_xor(spv[l], 2);
        spv[l] += __shfl_xor(spv[l], 4);  spv[l] += __shfl_xor(spv[l], 8);
        spv[l] += __shfl_xor(spv[l], 16); spv[l] += __shfl_xor(spv[l], 32);
    }
    if (lane == 0) {
#pragma unroll
        for (int l = 0; l < 16; l++) red[wv4][l] = spv[l];
    }
    __syncthreads();
    float w[16], se = 0.f;
    {
        float sc[16], m;
#pragma unroll
        for (int l = 0; l < 16; l++)
            sc[l] = (red[0][l] + red[1][l] + red[2][l] + red[3][l]) * 0.03125f;
        m = sc[0];
#pragma unroll
        for (int l = 1; l < 16; l++) m = fmaxf(m, sc[l]);
#pragma unroll
        for (int l = 0; l < 16; l++) { w[l] = __expf(sc[l] - m); se += w[l]; }
        float inv = 1.f / se;
#pragma unroll
        for (int l = 0; l < 16; l++) w[l] *= inv;
    }
    __hip_bfloat16 o4[4];
#pragma unroll
    for (int q = 0; q < 4; q++) {
        float s = 0.f;
#pragma unroll
        for (int l = 0; l < 8; l++) s += w[l] * (float)a[q][0][l];
#pragma unroll
        for (int l = 0; l < 8; l++) s += w[l + 8] * (float)a[q][1][l];
        o4[q] = __float2bfloat16(s);
    }
    *reinterpret_cast<uint2*>(hbt + (size_t)n * K2_ + H_ + tid * 4) =
        *reinterpret_cast<uint2*>(o4);
}

// ---------------- step GEMM + gates, XCD-clustered, 2 WGs/CU --------------
// 512 WGs x 256 thr. bid = xcd + 8*k; ct = (bid&7)+8*(k&7) (16 cols x 4
// sections), r = k>>3 (32 n-rows). Per-XCD: 8 W2T slices (2 MB) + hb (1 MB)
// L2-resident. K = 2048, BK = 128, double-buffered LDS (51 KB -> 2 WGs/CU).
#define LDAp 136

__global__ __launch_bounds__(256) void step_gemm(
    const __hip_bfloat16* __restrict__ hb_in,
    __hip_bfloat16* __restrict__ hb_out,
    const __hip_bfloat16* __restrict__ W2T,
    const __hip_bfloat16* __restrict__ xp,   // [256][4096] bf16, this t
    const float* __restrict__ bias,
    float* __restrict__ cbuf,
    float* __restrict__ out, int t)
{
    // A0 [0,8704) A1 [8704,17408) B0 [17408,34816) B1 [34816,52224)
    __shared__ __align__(16) char smem[52224];
    float* pls = (float*)smem;  // [32][68] fp32, aliases A0 after K-loop

    const int tid = threadIdx.x;
    const int lane = tid & 63, wv = tid >> 6;       // wv = gate section
    const int bid = blockIdx.x;
    const int k = bid >> 3;
    const int ct = (bid & 7) + 8 * (k & 7);         // 0..63, XCD = ct%8
    const int r  = k >> 3;                          // 0..7
    const int hc0 = ct * 16, n0 = r * 32;
    const int rs = tid >> 4;                        // 0..15
    const int kc = (tid & 15) * 8;
    const int l15 = lane & 15, ko8 = (lane >> 4) * 8;

    const __hip_bfloat16* aS0 = hb_in + (size_t)(n0 + rs) * K2_ + kc;
    const __hip_bfloat16* aS1 = hb_in + (size_t)(n0 + rs + 16) * K2_ + kc;
    const __hip_bfloat16* bS0 = W2T + (size_t)(0 * 1024 + hc0 + rs) * K2_ + kc;
    const __hip_bfloat16* bS1 = W2T + (size_t)(1 * 1024 + hc0 + rs) * K2_ + kc;
    const __hip_bfloat16* bS2 = W2T + (size_t)(2 * 1024 + hc0 + rs) * K2_ + kc;
    const __hip_bfloat16* bS3 = W2T + (size_t)(3 * 1024 + hc0 + rs) * K2_ + kc;

    int4 ra0, ra1, rb0, rb1, rb2, rb3;
    auto LOAD = [&](int k0) {
        ra0 = *reinterpret_cast<const int4*>(aS0 + k0);
        ra1 = *reinterpret_cast<const int4*>(aS1 + k0);
        rb0 = *reinterpret_cast<const int4*>(bS0 + k0);
        rb1 = *reinterpret_cast<const int4*>(bS1 + k0);
        rb2 = *reinterpret_cast<const int4*>(bS2 + k0);
        rb3 = *reinterpret_cast<const int4*>(bS3 + k0);
    };
    auto WRITE = [&](int b) {
        __hip_bfloat16* Al = (__hip_bfloat16*)(smem + b * 8704);
        __hip_bfloat16* Bl = (__hip_bfloat16*)(smem + 17408 + b * 17408);
        *reinterpret_cast<int4*>(Al + rs * LDAp + kc) = ra0;
        *reinterpret_cast<int4*>(Al + (rs + 16) * LDAp + kc) = ra1;
        *reinterpret_cast<int4*>(Bl + rs * LDAp + kc) = rb0;
        *reinterpret_cast<int4*>(Bl + (rs + 16) * LDAp + kc) = rb1;
        *reinterpret_cast<int4*>(Bl + (rs + 32) * LDAp + kc) = rb2;
        *reinterpret_cast<int4*>(Bl + (rs + 48) * LDAp + kc) = rb3;
    };

    LOAD(0);
    WRITE(0);
    __syncthreads();

    f32x4 acc0{}, acc1{};
#pragma unroll 1
    for (int it = 0; it < 16; ++it) {
        if (it < 15) LOAD((it + 1) * 128);
        const int cur = it & 1;
        const __hip_bfloat16* pA = (const __hip_bfloat16*)(smem + cur * 8704) + l15 * LDAp + ko8;
        const __hip_bfloat16* pB = (const __hip_bfloat16*)(smem + 17408 + cur * 17408)
                                   + (wv * 16 + l15) * LDAp + ko8;
#pragma unroll
        for (int kf = 0; kf < 4; kf++) {
            bf16x8 a0 = *reinterpret_cast<const bf16x8*>(pA + kf * 32);
            bf16x8 a1 = *reinterpret_cast<const bf16x8*>(pA + 16 * LDAp + kf * 32);
            bf16x8 bq = *reinterpret_cast<const bf16x8*>(pB + kf * 32);
            acc0 = __builtin_amdgcn_mfma_f32_16x16x32_bf16(a0, bq, acc0, 0, 0, 0);
            acc1 = __builtin_amdgcn_mfma_f32_16x16x32_bf16(a1, bq, acc1, 0, 0, 0);
        }
        __syncthreads();                 // all waves done reading buf[cur]
        if (it < 15) {
            WRITE(cur ^ 1);
            __syncthreads();             // next-buf writes visible
        }
    }

    // pls: [32 n][sec*16 + col]  (aliases A0; safe after final barrier)
    {
        const int cr = (lane >> 4) * 4;
#pragma unroll
        for (int r4 = 0; r4 < 4; r4++) {
            pls[(cr + r4) * 68 + wv * 16 + l15]      = acc0[r4];
            pls[(16 + cr + r4) * 68 + wv * 16 + l15] = acc1[r4];
        }
    }
    __syncthreads();

    // ---- epilogue: thread -> (n_l = tid>>3, 2 cols at (tid&7)*2) ----
    {
        const int n_l = tid >> 3, c2 = (tid & 7) * 2;
        const int nn = n0 + n_l;
        float hv2[2], cv2[2];
        const size_t cbase = (size_t)nn * H_ + hc0 + c2;
        float2 cold = *reinterpret_cast<const float2*>(cbuf + cbase);
        cv2[0] = cold.x; cv2[1] = cold.y;
#pragma unroll
        for (int cc = 0; cc < 2; cc++) {
            const int c = c2 + cc;
            float pre[4];
#pragma unroll
            for (int s = 0; s < 4; s++) {
                const int gj = s * 1024 + hc0 + c;
                pre[s] = pls[n_l * 68 + s * 16 + c]
                       + __bfloat162float(xp[(size_t)nn * FH_ + gj]) + bias[gj];
            }
            float iv = 1.f / (1.f + __expf(-pre[0]));
            float fv = 1.f / (1.f + __expf(-pre[1]));
            float ov = 1.f / (1.f + __expf(-pre[2]));
            float gx = fminf(fmaxf(pre[3], -20.f), 20.f);
            float eg = __expf(2.f * gx);
            float gv = (eg - 1.f) / (eg + 1.f);
            float c2v = fv * cv2[cc] + iv * gv;
            cv2[cc] = c2v;
            float cx = fminf(fmaxf(c2v, -20.f), 20.f);
            float ec = __expf(2.f * cx);
            hv2[cc] = ov * (ec - 1.f) / (ec + 1.f);
        }
        *reinterpret_cast<float2*>(cbuf + cbase) = make_float2(cv2[0], cv2[1]);
        *reinterpret_cast<float2*>(out + ((size_t)nn * T_ + t) * H_ + hc0 + c2) =
            make_float2(hv2[0], hv2[1]);
        __hip_bfloat16 h2[2];
        h2[0] = __float2bfloat16(hv2[0]);
        h2[1] = __float2bfloat16(hv2[1]);
        *reinterpret_cast<uint32_t*>(hb_out + (size_t)nn * K2_ + hc0 + c2) =
            *reinterpret_cast<uint32_t*>(h2);
    }
}

extern "C" void kernel_launch(void* const* d_in, const int* in_sizes, int n_in,
                              void* d_out, int out_size, void* d_ws, size_t ws_size,
                              hipStream_t stream)
{
    const float* x     = (const float*)d_in[0];
    const float* A     = (const float*)d_in[1];
    const float* Wx    = (const float*)d_in[2];
    const float* Wh    = (const float*)d_in[3];
    const float* Wattn = (const float*)d_in[4];
    const float* b     = (const float*)d_in[5];
    float* out = (float*)d_out;
    char* ws = (char*)d_ws;
    dim3 tb(32, 8);

    const size_t SZ_W2T = (size_t)FH_ * K2_ * 2;       // 16.8 MB  [Wh;Wattn]^T
    const size_t SZ_WxT = (size_t)FH_ * D_ * 2;        // 8.4 MB
    const size_t SZ_Abf = (size_t)N_ * H_ * 16 * 2;    // 8.4 MB
    const size_t SZ_HB  = (size_t)N_ * K2_ * 2;        // 1 MB (x2)
    const size_t SZ_C   = (size_t)N_ * H_ * 4;         // 1 MB
    const size_t SZ_XPT = (size_t)N_ * FH_ * 2;        // 2.1 MB per timestep

    size_t off = 0;
    __hip_bfloat16* W2T = (__hip_bfloat16*)(ws + off); off += SZ_W2T;
    __hip_bfloat16* WxT = (__hip_bfloat16*)(ws + off); off += SZ_WxT;
    __hip_bfloat16* Abf = (__hip_bfloat16*)(ws + off); off += SZ_Abf;
    __hip_bfloat16* hbA = (__hip_bfloat16*)(ws + off); off += SZ_HB;
    __hip_bfloat16* hbB = (__hip_bfloat16*)(ws + off); off += SZ_HB;
    float* cbuf = (float*)(ws + off); off += SZ_C;
    __hip_bfloat16* xpb = (__hip_bfloat16*)(ws + off);

    size_t rem = (ws_size > off) ? (ws_size - off) : 0;
    int TC = 64;
    while (TC > 1 && (size_t)TC * SZ_XPT > rem) TC >>= 1;

    // ---- weight / A prep ----
    transpose_cast<<<dim3(FH_ / 32, H_ / 32), tb, 0, stream>>>(Wh, FH_, W2T, K2_, 0);
    transpose_cast<<<dim3(FH_ / 32, H_ / 32), tb, 0, stream>>>(Wattn, FH_, W2T, K2_, H_);
    transpose_cast<<<dim3(FH_ / 32, D_ / 32), tb, 0, stream>>>(Wx, FH_, WxT, D_, 0);
    abf_cast<<<dim3((N_ * H_ * 16) / 1024), 256, 0, stream>>>(A, Abf);
    init_p<<<N_, 256, 0, stream>>>(A, cbuf, hbA);

    __hip_bfloat16* hbp[2] = {hbA, hbB};
    for (int t0 = 0; t0 < T_; t0 += TC) {
        int tc = (T_ - t0 < TC) ? (T_ - t0) : TC;
        gemm_x<<<dim3(FH_ / BN, tc * N_ / BM), 256, 0, stream>>>(x, WxT, xpb, t0);
        for (int tl = 0; tl < tc; tl++) {
            int t = t0 + tl;
            // scores + softmax + attn for step t (fills attn-half of hb[t&1])
            wattn2<<<N_, 256, 0, stream>>>(hbp[t & 1], Abf);
            // GEMM K=2048 + gates; writes h-half of hb[(t+1)&1]
            step_gemm<<<dim3(512), 256, 0, stream>>>(
                hbp[t & 1], hbp[(t + 1) & 1], W2T,
                xpb + (size_t)tl * N_ * FH_, b, cbuf, out, t);
        }
    }
}